// Round 3
// baseline (395.260 us; speedup 1.0000x reference)
//
#include <hip/hip_runtime.h>
#include <math.h>

// Problem constants: B=8, T=16, P=197, C=1024, R=8
#define BB 8
#define TT 16
#define PP 197
#define CC 1024
#define RR 8
#define NSEQ  (BB * PP)          // 1576 sequences = 1576 blocks
#define LORA_SCALE 2.0f          // alpha/rank = 16/8

__device__ __forceinline__ float sigf(float x) {
    x = fminf(fmaxf(x, -30.f), 30.f);
    return 1.0f / (1.0f + __expf(-x));
}
__device__ __forceinline__ float tanh_fast(float x) {
    x = fminf(fmaxf(x, -15.f), 15.f);
    float e = __expf(-2.0f * x);
    return (1.0f - e) / (1.0f + e);
}
__device__ __forceinline__ float dot4(const float4 a, const float4 b) {
    return a.x * b.x + a.y * b.y + a.z * b.z + a.w * b.w;
}

// ---------------------------------------------------------------------------
// Fully fused, 4 waves per sequence-block (vs round-0's 1 wave: occupancy was
// the diagnosed bottleneck at 14.5%). Zero kernel boundaries (the round-1
// 3-kernel split cost ~+10us in drain/launch tax despite full occupancy).
//   Phase 1 (down): wave w owns t=4w..4w+3 as two 2-row batches; dw streamed
//     from L1/L2 (32KB, shared by all blocks -> cache-resident; no LDS stage
//     so LDS stays 1KB and occupancy is VGPR-bound only).
//   Phase 2 (LSTM): wave 0 only; lane = gate*8+rank (idx=lane&31): 16 weight
//     regs/lane, gate activations exchanged with 3 shfls. Keeps kernel-wide
//     VGPR ~<=80 (the round-0 scheme needed 64 regs of weights per lane).
//   Phase 3 (up): per-g4-chunk up columns streamed from L2 (coalesced 128B/
//     lane), h broadcast from LDS, float4 stores (1KB/wave-instr).
// VGPR target <=85 -> ~24 waves/CU; 1576 blocks ~ 6.2/CU fully resident.
// ---------------------------------------------------------------------------
__global__ __launch_bounds__(256, 6) void k_fused2(const float* __restrict__ hs,
                                                   const float* __restrict__ fm,
                                                   const float* __restrict__ dw,
                                                   const float* __restrict__ w_ih,
                                                   const float* __restrict__ w_hh,
                                                   const float* __restrict__ b_ih,
                                                   const float* __restrict__ b_hh,
                                                   const float* __restrict__ up,
                                                   float* __restrict__ out) {
    __shared__ float red_lds[TT][RR];   // masked down-projection
    __shared__ float h_lds[TT][RR];     // masked+scaled hidden states

    const int tid  = threadIdx.x;
    const int lane = tid & 63;
    const int wv   = tid >> 6;          // 0..3
    const int seq  = blockIdx.x;
    const int b    = seq / PP;
    const int p    = seq - b * PP;
    const float* hsbase = hs + ((size_t)b * TT * PP + p) * CC;  // t-stride = PP*CC

    // ---- Phase 1: LoRA down. Wave wv: t = 4*wv + {0,1,2,3}, 2-row batches ----
#pragma unroll
    for (int batch = 0; batch < 2; ++batch) {
        const int t0 = wv * 4 + batch * 2;
        float4 xr[2][4];
#pragma unroll
        for (int i = 0; i < 2; ++i) {
            const float* rp = hsbase + (size_t)(t0 + i) * PP * CC;
#pragma unroll
            for (int k = 0; k < 4; ++k)
                xr[i][k] = *(const float4*)(rp + k * 256 + lane * 4);
        }
        float acc[2][RR];
#pragma unroll
        for (int i = 0; i < 2; ++i)
#pragma unroll
            for (int r = 0; r < RR; ++r) acc[i][r] = 0.f;
#pragma unroll
        for (int r = 0; r < RR; ++r)
#pragma unroll
            for (int k = 0; k < 4; ++k) {
                const float4 w = *(const float4*)(dw + r * CC + k * 256 + lane * 4);
                acc[0][r] += dot4(xr[0][k], w);
                acc[1][r] += dot4(xr[1][k], w);
            }
#pragma unroll
        for (int d = 32; d >= 1; d >>= 1)
#pragma unroll
            for (int i = 0; i < 2; ++i)
#pragma unroll
                for (int r = 0; r < RR; ++r)
                    acc[i][r] += __shfl_xor(acc[i][r], d, 64);
        if (lane == 0) {
#pragma unroll
            for (int i = 0; i < 2; ++i) {
                const float m = fm[b * TT + t0 + i];
                *(float4*)&red_lds[t0 + i][0] = make_float4(acc[i][0] * m, acc[i][1] * m,
                                                            acc[i][2] * m, acc[i][3] * m);
                *(float4*)&red_lds[t0 + i][4] = make_float4(acc[i][4] * m, acc[i][5] * m,
                                                            acc[i][6] * m, acc[i][7] * m);
            }
        }
    }
    __syncthreads();

    // ---- Phase 2: LSTM on wave 0; lane idx = gate*8 + rank ----
    if (wv == 0) {
        const int idx = lane & 31;          // lanes 32..63 mirror 0..31 (harmless)
        const int r   = idx & 7;
        const bool isG = (idx >> 3) == 2;   // gate order i,f,g,o; 'g' uses tanh
        float wr[8], whv[8];
        {
            const float* wip = w_ih + idx * 8;
            float4 a = *(const float4*)wip, b4 = *(const float4*)(wip + 4);
            wr[0] = a.x;  wr[1] = a.y;  wr[2] = a.z;  wr[3] = a.w;
            wr[4] = b4.x; wr[5] = b4.y; wr[6] = b4.z; wr[7] = b4.w;
            const float* whp = w_hh + idx * 8;
            float4 c4 = *(const float4*)whp, d4 = *(const float4*)(whp + 4);
            whv[0] = c4.x; whv[1] = c4.y; whv[2] = c4.z; whv[3] = c4.w;
            whv[4] = d4.x; whv[5] = d4.y; whv[6] = d4.z; whv[7] = d4.w;
        }
        const float bias = b_ih[idx] + b_hh[idx];

        float h = 0.f, c = 0.f;
#pragma unroll
        for (int t = 0; t < TT; ++t) {
            const float4 x0 = *(const float4*)&red_lds[t][0];   // broadcast read
            const float4 x1 = *(const float4*)&red_lds[t][4];
            const float xs[8] = {x0.x, x0.y, x0.z, x0.w, x1.x, x1.y, x1.z, x1.w};
            float gv = bias;
#pragma unroll
            for (int j = 0; j < 8; ++j) gv += wr[j] * xs[j];     // off-chain
#pragma unroll
            for (int j = 0; j < 8; ++j) gv += whv[j] * __shfl(h, j, 64);  // h chain
            const float sg = sigf(gv);
            const float tg = tanh_fast(gv);
            const float a  = isG ? tg : sg;                      // this lane's gate act
            const float fa = __shfl(a,  8 + r, 64);              // f-act of rank r
            const float ga = __shfl(a, 16 + r, 64);              // g-act
            const float oa = __shfl(a, 24 + r, 64);              // o-act
            c = fa * c + a * ga;          // valid on lanes idx<8 (a = i-act there)
            h = oa * tanh_fast(c);        // recurrent h is UNmasked (matches ref)
            if (lane < 8) h_lds[t][lane] = h * fm[b * TT + t] * LORA_SCALE;
        }
    }
    __syncthreads();

    // ---- Phase 3: LoRA up. Wave wv: t = 4*wv + {0,1,2,3} ----
    float* obase = out + ((size_t)b * TT * PP + p) * CC;
#pragma unroll
    for (int g4 = 0; g4 < 4; ++g4) {
        // up rows for the 4 consecutive output cols this lane owns: 128B coalesced
        const float* wp = up + (size_t)(g4 * 256 + lane * 4) * RR;
        float4 wA[4], wB[4];
#pragma unroll
        for (int c4 = 0; c4 < 4; ++c4) {
            wA[c4] = *(const float4*)(wp + c4 * RR);
            wB[c4] = *(const float4*)(wp + c4 * RR + 4);
        }
#pragma unroll
        for (int i = 0; i < 4; ++i) {
            const int t = wv * 4 + i;
            const float4 h0 = *(const float4*)&h_lds[t][0];      // broadcast read
            const float4 h1 = *(const float4*)&h_lds[t][4];
            float4 o;
            o.x = dot4(h0, wA[0]) + dot4(h1, wB[0]);
            o.y = dot4(h0, wA[1]) + dot4(h1, wB[1]);
            o.z = dot4(h0, wA[2]) + dot4(h1, wB[2]);
            o.w = dot4(h0, wA[3]) + dot4(h1, wB[3]);
            *(float4*)(obase + (size_t)t * PP * CC + g4 * 256 + lane * 4) = o;
        }
    }
}

extern "C" void kernel_launch(void* const* d_in, const int* in_sizes, int n_in,
                              void* d_out, int out_size, void* d_ws, size_t ws_size,
                              hipStream_t stream) {
    const float* hs  = (const float*)d_in[0];  // (B,T,P,C)
    const float* fm  = (const float*)d_in[2];  // (B,T)
    const float* dw  = (const float*)d_in[3];  // (R,C)
    const float* wih = (const float*)d_in[4];  // (4R,R)
    const float* whh = (const float*)d_in[5];  // (4R,R)
    const float* bih = (const float*)d_in[6];  // (4R,)
    const float* bhh = (const float*)d_in[7];  // (4R,)
    const float* up  = (const float*)d_in[8];  // (C,R)
    float* out = (float*)d_out;

    (void)d_ws; (void)ws_size;   // the 413MB poison fill is unconditional; ws unused

    // One 4-wave block per sequence: single launch, no inter-kernel drains.
    k_fused2<<<NSEQ, 256, 0, stream>>>(hs, fm, dw, wih, whh, bih, bhh, up, out);
}

// Round 4
// 265.913 us; speedup vs baseline: 1.4864x; 1.4864x over previous
//
#include <hip/hip_runtime.h>
#include <math.h>

// Problem constants: B=8, T=16, P=197, C=1024, R=8
#define BB 8
#define TT 16
#define PP 197
#define CC 1024
#define RR 8
#define NSEQ  (BB * PP)          // 1576 sequences = 1576 blocks
#define LORA_SCALE 2.0f          // alpha/rank = 16/8

__device__ __forceinline__ float sigf(float x) {
    x = fminf(fmaxf(x, -30.f), 30.f);
    return 1.0f / (1.0f + __expf(-x));
}
__device__ __forceinline__ float tanh_fast(float x) {
    x = fminf(fmaxf(x, -15.f), 15.f);
    float e = __expf(-2.0f * x);
    return (1.0f - e) / (1.0f + e);
}
__device__ __forceinline__ float dot4(const float4 a, const float4 b) {
    return a.x * b.x + a.y * b.y + a.z * b.z + a.w * b.w;
}

// ---------------------------------------------------------------------------
// Fully fused, 4 waves per sequence-block. Round-3 post-mortem: the identical
// structure with __launch_bounds__(256,6) capped VGPRs at 512/6~85 < the ~110
// live registers the phases need -> compiler demoted xr/wA/wB to scratch
// (VGPR_Count=40, FETCH 275MB, WRITE 535MB of spill traffic, 289us).
// Fix: (256,4) -> VGPR cap 128, fits with margin. 16 waves/CU is still 10x
// round-0's occupancy and plenty to cover the two memory-bound phases.
//   Phase 1 (down): wave w owns t=4w..4w+3 as two 2-row batches; dw streamed
//     from L1/L2 (32KB, shared by every block -> cache-resident).
//   Phase 2 (LSTM): wave 0 only; lane = gate*8+rank: 16 weight regs/lane,
//     gate activations exchanged with 3 shfls.
//   Phase 3 (up): per-g4-chunk up columns streamed from L2 (128B/lane
//     coalesced), h broadcast from LDS, float4 stores (1KB/wave-instr).
// ---------------------------------------------------------------------------
__global__ __launch_bounds__(256, 4) void k_fused2(const float* __restrict__ hs,
                                                   const float* __restrict__ fm,
                                                   const float* __restrict__ dw,
                                                   const float* __restrict__ w_ih,
                                                   const float* __restrict__ w_hh,
                                                   const float* __restrict__ b_ih,
                                                   const float* __restrict__ b_hh,
                                                   const float* __restrict__ up,
                                                   float* __restrict__ out) {
    __shared__ float red_lds[TT][RR];   // masked down-projection
    __shared__ float h_lds[TT][RR];     // masked+scaled hidden states

    const int tid  = threadIdx.x;
    const int lane = tid & 63;
    const int wv   = tid >> 6;          // 0..3
    const int seq  = blockIdx.x;
    const int b    = seq / PP;
    const int p    = seq - b * PP;
    const float* hsbase = hs + ((size_t)b * TT * PP + p) * CC;  // t-stride = PP*CC

    // ---- Phase 1: LoRA down. Wave wv: t = 4*wv + {0,1,2,3}, 2-row batches ----
#pragma unroll
    for (int batch = 0; batch < 2; ++batch) {
        const int t0 = wv * 4 + batch * 2;
        float4 xr[2][4];
#pragma unroll
        for (int i = 0; i < 2; ++i) {
            const float* rp = hsbase + (size_t)(t0 + i) * PP * CC;
#pragma unroll
            for (int k = 0; k < 4; ++k)
                xr[i][k] = *(const float4*)(rp + k * 256 + lane * 4);
        }
        float acc[2][RR];
#pragma unroll
        for (int i = 0; i < 2; ++i)
#pragma unroll
            for (int r = 0; r < RR; ++r) acc[i][r] = 0.f;
#pragma unroll
        for (int r = 0; r < RR; ++r)
#pragma unroll
            for (int k = 0; k < 4; ++k) {
                const float4 w = *(const float4*)(dw + r * CC + k * 256 + lane * 4);
                acc[0][r] += dot4(xr[0][k], w);
                acc[1][r] += dot4(xr[1][k], w);
            }
#pragma unroll
        for (int d = 32; d >= 1; d >>= 1)
#pragma unroll
            for (int i = 0; i < 2; ++i)
#pragma unroll
                for (int r = 0; r < RR; ++r)
                    acc[i][r] += __shfl_xor(acc[i][r], d, 64);
        if (lane == 0) {
#pragma unroll
            for (int i = 0; i < 2; ++i) {
                const float m = fm[b * TT + t0 + i];
                *(float4*)&red_lds[t0 + i][0] = make_float4(acc[i][0] * m, acc[i][1] * m,
                                                            acc[i][2] * m, acc[i][3] * m);
                *(float4*)&red_lds[t0 + i][4] = make_float4(acc[i][4] * m, acc[i][5] * m,
                                                            acc[i][6] * m, acc[i][7] * m);
            }
        }
    }
    __syncthreads();

    // ---- Phase 2: LSTM on wave 0; lane idx = gate*8 + rank ----
    if (wv == 0) {
        const int idx = lane & 31;          // lanes 32..63 mirror 0..31 (harmless)
        const int r   = idx & 7;
        const bool isG = (idx >> 3) == 2;   // gate order i,f,g,o; 'g' uses tanh
        float wr[8], whv[8];
        {
            const float* wip = w_ih + idx * 8;
            float4 a = *(const float4*)wip, b4 = *(const float4*)(wip + 4);
            wr[0] = a.x;  wr[1] = a.y;  wr[2] = a.z;  wr[3] = a.w;
            wr[4] = b4.x; wr[5] = b4.y; wr[6] = b4.z; wr[7] = b4.w;
            const float* whp = w_hh + idx * 8;
            float4 c4 = *(const float4*)whp, d4 = *(const float4*)(whp + 4);
            whv[0] = c4.x; whv[1] = c4.y; whv[2] = c4.z; whv[3] = c4.w;
            whv[4] = d4.x; whv[5] = d4.y; whv[6] = d4.z; whv[7] = d4.w;
        }
        const float bias = b_ih[idx] + b_hh[idx];

        float h = 0.f, c = 0.f;
#pragma unroll
        for (int t = 0; t < TT; ++t) {
            const float4 x0 = *(const float4*)&red_lds[t][0];   // broadcast read
            const float4 x1 = *(const float4*)&red_lds[t][4];
            const float xs[8] = {x0.x, x0.y, x0.z, x0.w, x1.x, x1.y, x1.z, x1.w};
            float gv = bias;
#pragma unroll
            for (int j = 0; j < 8; ++j) gv += wr[j] * xs[j];     // off-chain
#pragma unroll
            for (int j = 0; j < 8; ++j) gv += whv[j] * __shfl(h, j, 64);  // h chain
            const float sg = sigf(gv);
            const float tg = tanh_fast(gv);
            const float a  = isG ? tg : sg;                      // this lane's gate act
            const float fa = __shfl(a,  8 + r, 64);              // f-act of rank r
            const float ga = __shfl(a, 16 + r, 64);              // g-act
            const float oa = __shfl(a, 24 + r, 64);              // o-act
            c = fa * c + a * ga;          // valid on lanes idx<8 (a = i-act there)
            h = oa * tanh_fast(c);        // recurrent h is UNmasked (matches ref)
            if (lane < 8) h_lds[t][lane] = h * fm[b * TT + t] * LORA_SCALE;
        }
    }
    __syncthreads();

    // ---- Phase 3: LoRA up. Wave wv: t = 4*wv + {0,1,2,3} ----
    float* obase = out + ((size_t)b * TT * PP + p) * CC;
#pragma unroll
    for (int g4 = 0; g4 < 4; ++g4) {
        // up rows for the 4 consecutive output cols this lane owns: 128B coalesced
        const float* wp = up + (size_t)(g4 * 256 + lane * 4) * RR;
        float4 wA[4], wB[4];
#pragma unroll
        for (int c4 = 0; c4 < 4; ++c4) {
            wA[c4] = *(const float4*)(wp + c4 * RR);
            wB[c4] = *(const float4*)(wp + c4 * RR + 4);
        }
#pragma unroll
        for (int i = 0; i < 4; ++i) {
            const int t = wv * 4 + i;
            const float4 h0 = *(const float4*)&h_lds[t][0];      // broadcast read
            const float4 h1 = *(const float4*)&h_lds[t][4];
            float4 o;
            o.x = dot4(h0, wA[0]) + dot4(h1, wB[0]);
            o.y = dot4(h0, wA[1]) + dot4(h1, wB[1]);
            o.z = dot4(h0, wA[2]) + dot4(h1, wB[2]);
            o.w = dot4(h0, wA[3]) + dot4(h1, wB[3]);
            *(float4*)(obase + (size_t)t * PP * CC + g4 * 256 + lane * 4) = o;
        }
    }
}

extern "C" void kernel_launch(void* const* d_in, const int* in_sizes, int n_in,
                              void* d_out, int out_size, void* d_ws, size_t ws_size,
                              hipStream_t stream) {
    const float* hs  = (const float*)d_in[0];  // (B,T,P,C)
    const float* fm  = (const float*)d_in[2];  // (B,T)
    const float* dw  = (const float*)d_in[3];  // (R,C)
    const float* wih = (const float*)d_in[4];  // (4R,R)
    const float* whh = (const float*)d_in[5];  // (4R,R)
    const float* bih = (const float*)d_in[6];  // (4R,)
    const float* bhh = (const float*)d_in[7];  // (4R,)
    const float* up  = (const float*)d_in[8];  // (C,R)
    float* out = (float*)d_out;

    (void)d_ws; (void)ws_size;   // the 413MB poison fill is unconditional; ws unused

    // One 4-wave block per sequence: single launch, no inter-kernel drains.
    k_fused2<<<NSEQ, 256, 0, stream>>>(hs, fm, dw, wih, whh, bih, bhh, up, out);
}

// Round 6
// 218.114 us; speedup vs baseline: 1.8122x; 1.2191x over previous
//
#include <hip/hip_runtime.h>
#include <math.h>

// Problem constants: B=8, T=16, P=197, C=1024, R=8
#define BB 8
#define TT 16
#define PP 197
#define CC 1024
#define RR 8
#define NSEQ  (BB * PP)          // 1576 sequences = 1576 blocks
#define LORA_SCALE 2.0f          // alpha/rank = 16/8

__device__ __forceinline__ float sigf(float x) {
    x = fminf(fmaxf(x, -30.f), 30.f);
    return 1.0f / (1.0f + __expf(-x));
}
__device__ __forceinline__ float tanh_fast(float x) {
    x = fminf(fmaxf(x, -15.f), 15.f);
    float e = __expf(-2.0f * x);
    return (1.0f - e) / (1.0f + e);
}
__device__ __forceinline__ float dot4(const float4 a, const float4 b) {
    return a.x * b.x + a.y * b.y + a.z * b.z + a.w * b.w;
}

// ---------------------------------------------------------------------------
// Fused, 4 waves/sequence-block, LDS-resident weights.  (Resubmission of the
// round-5 kernel: the round-5 bench died on container acquisition, giving no
// kernel signal; source audited for hang/fault hazards -- barriers uniform,
// LDS in bounds, 16B-aligned accesses -- and resubmitted unchanged.)
// R4 post-mortem: (a) compiler allocates ~half the launch_bounds VGPR cap
// (cap128->64) and spills the rest (67MB extra WRITE); (b) dw was re-streamed
// 8x32KB per block from L1/L2.  Fix: dw staged once into 32KB LDS (reused as
// transposed upT for phase 3), peak live regs ~80, bound (256,2) so cap=256
// and the half-cap heuristic still lands >=128 -> no scratch.
//   Phase 1 (down): wave wv owns t=4wv..4wv+3 in two 2-row batches; 8 float4
//     HBM loads in flight/lane; weights via conflict-free ds_read_b128.
//   Phase 2 (LSTM): wave 0, lane=gate*8+rank, 3-shfl activation exchange
//     (identical to R4 -- numerically verified, absmax 2.4e-4).
//   Phase 3 (up): smem re-staged as upT[8][1024]; per g4: w[8] hoisted, 4
//     float4 stores/lane.  All out stores 1KB/wave-instr coalesced.
// ---------------------------------------------------------------------------
__global__ __launch_bounds__(256, 2) void k_fused3(const float* __restrict__ hs,
                                                   const float* __restrict__ fm,
                                                   const float* __restrict__ dw,
                                                   const float* __restrict__ w_ih,
                                                   const float* __restrict__ w_hh,
                                                   const float* __restrict__ b_ih,
                                                   const float* __restrict__ b_hh,
                                                   const float* __restrict__ up,
                                                   float* __restrict__ out) {
    __shared__ float smem[8192];        // 32 KB: dw in phase 1, upT in phase 3
    __shared__ float red_lds[TT][RR];   // masked down-projection
    __shared__ float h_lds[TT][RR];     // masked+scaled hidden states

    const int tid  = threadIdx.x;
    const int lane = tid & 63;
    const int wv   = tid >> 6;          // 0..3
    const int seq  = blockIdx.x;
    const int b    = seq / PP;
    const int p    = seq - b * PP;
    const float* hsbase = hs + ((size_t)b * TT * PP + p) * CC;  // t-stride = PP*CC

    // ---- Stage dw (R,C) into LDS as float4[2048] ----
    {
        float4* w4 = (float4*)smem;
        const float4* src = (const float4*)dw;
#pragma unroll
        for (int j = 0; j < 8; ++j) w4[tid + j * 256] = src[tid + j * 256];
    }
    __syncthreads();

    // ---- Phase 1: LoRA down. Wave wv: t = 4wv+{0..3} in two 2-row batches ----
    {
        const float4* w4 = (const float4*)smem;
#pragma unroll
        for (int batch = 0; batch < 2; ++batch) {
            const int t0 = wv * 4 + batch * 2;
            float4 xr[2][4];
#pragma unroll
            for (int i = 0; i < 2; ++i) {
                const float* rp = hsbase + (size_t)(t0 + i) * PP * CC;
#pragma unroll
                for (int k = 0; k < 4; ++k)
                    xr[i][k] = *(const float4*)(rp + k * 256 + lane * 4);
            }
            float acc[2][RR];
#pragma unroll
            for (int i = 0; i < 2; ++i)
#pragma unroll
                for (int r = 0; r < RR; ++r) acc[i][r] = 0.f;
#pragma unroll
            for (int r = 0; r < RR; ++r)
#pragma unroll
                for (int k = 0; k < 4; ++k) {
                    const float4 w = w4[r * 256 + k * 64 + lane];   // stride-1: conflict-free
                    acc[0][r] += dot4(xr[0][k], w);
                    acc[1][r] += dot4(xr[1][k], w);
                }
#pragma unroll
            for (int d = 32; d >= 1; d >>= 1)
#pragma unroll
                for (int i = 0; i < 2; ++i)
#pragma unroll
                    for (int r = 0; r < RR; ++r)
                        acc[i][r] += __shfl_xor(acc[i][r], d, 64);
            if (lane == 0) {
#pragma unroll
                for (int i = 0; i < 2; ++i) {
                    const float m = fm[b * TT + t0 + i];
                    *(float4*)&red_lds[t0 + i][0] = make_float4(acc[i][0] * m, acc[i][1] * m,
                                                                acc[i][2] * m, acc[i][3] * m);
                    *(float4*)&red_lds[t0 + i][4] = make_float4(acc[i][4] * m, acc[i][5] * m,
                                                                acc[i][6] * m, acc[i][7] * m);
                }
            }
        }
    }
    __syncthreads();

    // ---- Phase 2: LSTM on wave 0; lane idx = gate*8 + rank ----
    if (wv == 0) {
        const int idx = lane & 31;          // lanes 32..63 mirror 0..31 (harmless)
        const int r   = idx & 7;
        const bool isG = (idx >> 3) == 2;   // gate order i,f,g,o; 'g' uses tanh
        float wr[8], whv[8];
        {
            const float* wip = w_ih + idx * 8;
            float4 a = *(const float4*)wip, b4 = *(const float4*)(wip + 4);
            wr[0] = a.x;  wr[1] = a.y;  wr[2] = a.z;  wr[3] = a.w;
            wr[4] = b4.x; wr[5] = b4.y; wr[6] = b4.z; wr[7] = b4.w;
            const float* whp = w_hh + idx * 8;
            float4 c4 = *(const float4*)whp, d4 = *(const float4*)(whp + 4);
            whv[0] = c4.x; whv[1] = c4.y; whv[2] = c4.z; whv[3] = c4.w;
            whv[4] = d4.x; whv[5] = d4.y; whv[6] = d4.z; whv[7] = d4.w;
        }
        const float bias = b_ih[idx] + b_hh[idx];

        float h = 0.f, c = 0.f;
#pragma unroll
        for (int t = 0; t < TT; ++t) {
            const float4 x0 = *(const float4*)&red_lds[t][0];   // broadcast read
            const float4 x1 = *(const float4*)&red_lds[t][4];
            const float xs[8] = {x0.x, x0.y, x0.z, x0.w, x1.x, x1.y, x1.z, x1.w};
            float gv = bias;
#pragma unroll
            for (int j = 0; j < 8; ++j) gv += wr[j] * xs[j];     // off-chain
#pragma unroll
            for (int j = 0; j < 8; ++j) gv += whv[j] * __shfl(h, j, 64);  // h chain
            const float sg = sigf(gv);
            const float tg = tanh_fast(gv);
            const float a  = isG ? tg : sg;                      // this lane's gate act
            const float fa = __shfl(a,  8 + r, 64);              // f-act of rank r
            const float ga = __shfl(a, 16 + r, 64);              // g-act
            const float oa = __shfl(a, 24 + r, 64);              // o-act
            c = fa * c + a * ga;          // valid on lanes idx<8 (a = i-act there)
            h = oa * tanh_fast(c);        // recurrent h is UNmasked (matches ref)
            if (lane < 8) h_lds[t][lane] = h * fm[b * TT + t] * LORA_SCALE;
        }
    }
    __syncthreads();

    // ---- Re-stage smem as upT[8][1024] (transposed up) ----
#pragma unroll
    for (int c0 = tid; c0 < CC; c0 += 256) {
        const float4 a  = *(const float4*)(up + (size_t)c0 * RR);
        const float4 b4 = *(const float4*)(up + (size_t)c0 * RR + 4);
        smem[0 * 1024 + c0] = a.x;  smem[1 * 1024 + c0] = a.y;
        smem[2 * 1024 + c0] = a.z;  smem[3 * 1024 + c0] = a.w;
        smem[4 * 1024 + c0] = b4.x; smem[5 * 1024 + c0] = b4.y;
        smem[6 * 1024 + c0] = b4.z; smem[7 * 1024 + c0] = b4.w;
    }
    __syncthreads();

    // ---- Phase 3: LoRA up. Wave wv: t = 4wv+{0..3} ----
    {
        const int t0 = wv * 4;
        float4 h0[4], h1[4];
#pragma unroll
        for (int i = 0; i < 4; ++i) {
            h0[i] = *(const float4*)&h_lds[t0 + i][0];           // broadcast read
            h1[i] = *(const float4*)&h_lds[t0 + i][4];
        }
        float* obase = out + ((size_t)b * TT * PP + p) * CC;
#pragma unroll
        for (int g4 = 0; g4 < 4; ++g4) {
            float4 w[8];
#pragma unroll
            for (int r = 0; r < 8; ++r)
                w[r] = *(const float4*)&smem[r * 1024 + g4 * 256 + lane * 4];
#pragma unroll
            for (int i = 0; i < 4; ++i) {
                const float hv[8] = {h0[i].x, h0[i].y, h0[i].z, h0[i].w,
                                     h1[i].x, h1[i].y, h1[i].z, h1[i].w};
                float4 o = make_float4(0.f, 0.f, 0.f, 0.f);
#pragma unroll
                for (int r = 0; r < 8; ++r) {
                    o.x += hv[r] * w[r].x;
                    o.y += hv[r] * w[r].y;
                    o.z += hv[r] * w[r].z;
                    o.w += hv[r] * w[r].w;
                }
                *(float4*)(obase + (size_t)(t0 + i) * PP * CC + g4 * 256 + lane * 4) = o;
            }
        }
    }
}

extern "C" void kernel_launch(void* const* d_in, const int* in_sizes, int n_in,
                              void* d_out, int out_size, void* d_ws, size_t ws_size,
                              hipStream_t stream) {
    const float* hs  = (const float*)d_in[0];  // (B,T,P,C)
    const float* fm  = (const float*)d_in[2];  // (B,T)
    const float* dw  = (const float*)d_in[3];  // (R,C)
    const float* wih = (const float*)d_in[4];  // (4R,R)
    const float* whh = (const float*)d_in[5];  // (4R,R)
    const float* bih = (const float*)d_in[6];  // (4R,)
    const float* bhh = (const float*)d_in[7];  // (4R,)
    const float* up  = (const float*)d_in[8];  // (C,R)
    float* out = (float*)d_out;

    (void)d_ws; (void)ws_size;   // the 413MB poison fill is unconditional; ws unused

    // One 4-wave block per sequence: single launch, no inter-kernel drains.
    k_fused3<<<NSEQ, 256, 0, stream>>>(hs, fm, dw, wih, whh, bih, bhh, up, out);
}